// Round 9
// baseline (80.909 us; speedup 1.0000x reference)
//
#include <hip/hip_runtime.h>
#include <hip/hip_bf16.h>
#include <math.h>

// CrossAttentionModule: 3D neighborhood attention (NATTEN-style clamped window)
// B=1, C=64, D=64, H=64, W=8, HEADS=8, hd=8, K=(3,3,3), dil=1.
//
// R9: attn gathers were HBM-latency-bound (R8: 51us, 285 GB/s, 14 MB).
// Now each attn block STAGES its K/V halo (2x4 tile -> 4x6x8 rows, 48 KB)
// into LDS via contiguous streamed uint4 loads, then gathers from LDS.
// q/k/v stay bf16 in ws. k_qkv gets matching d-slab<->XCD alignment.

#define PD 64
#define PH 64
#define PW 8
#define PTOT (PD*PH*PW)   // 32768
#define NC 64
#define NHEADS 8
#define HD 8
#define ATT_SCALE 0.35355339059327373f  // 1/sqrt(8)

#define TD 2              // d-extent of attn tile
#define TH 4              // h-extent
#define SD 4              // staged d extent (TD+2)
#define SH 6              // staged h extent (TH+2)
#define SROWS (SD*SH*PW)  // 192 staged position-rows

// ws layout (floats)
#define WS_MR   0                        // 128 tc x {mean,rstd}
#define WS_Q16  1024                     // PTOT*64 ushorts = PTOT*32 floats
#define WS_K16  (WS_Q16 + PTOT*32)
#define WS_V16  (WS_K16 + PTOT*32)

__device__ __forceinline__ void unpack8(uint4 u, float f[8]) {
  union { unsigned int i; float x; } a;
  a.i = u.x << 16;          f[0] = a.x;
  a.i = u.x & 0xffff0000u;  f[1] = a.x;
  a.i = u.y << 16;          f[2] = a.x;
  a.i = u.y & 0xffff0000u;  f[3] = a.x;
  a.i = u.z << 16;          f[4] = a.x;
  a.i = u.z & 0xffff0000u;  f[5] = a.x;
  a.i = u.w << 16;          f[6] = a.x;
  a.i = u.w & 0xffff0000u;  f[7] = a.x;
}

__global__ __launch_bounds__(1024) void k_stats(const float* __restrict__ skip,
                                                const float* __restrict__ up,
                                                float* __restrict__ ws) {
  int tc = blockIdx.x;                // 0..127
  const float* src = (tc < 64) ? (skip + (size_t)tc * PTOT)
                               : (up + (size_t)(tc - 64) * PTOT);
  const float4* b4 = (const float4*)src;
  float s1 = 0.f, s2 = 0.f;
  #pragma unroll
  for (int it = 0; it < 8; it++) {
    float4 v = b4[it * 1024 + threadIdx.x];
    s1 += v.x + v.y + v.z + v.w;
    s2 += v.x*v.x + v.y*v.y + v.z*v.z + v.w*v.w;
  }
  #pragma unroll
  for (int off = 32; off; off >>= 1) {
    s1 += __shfl_down(s1, off);
    s2 += __shfl_down(s2, off);
  }
  __shared__ float red[32];
  int wid = threadIdx.x >> 6;
  if ((threadIdx.x & 63) == 0) { red[wid*2] = s1; red[wid*2+1] = s2; }
  __syncthreads();
  if (threadIdx.x == 0) {
    float a = 0.f, b = 0.f;
    #pragma unroll
    for (int w2 = 0; w2 < 16; w2++) { a += red[w2*2]; b += red[w2*2+1]; }
    float mean = a / (float)PTOT;
    float var  = b / (float)PTOT - mean*mean;   // population var (ddof=0)
    ws[WS_MR + tc*2]     = mean;
    ws[WS_MR + tc*2 + 1] = rsqrtf(var + 1e-5f);
  }
}

// Fused inorm + QK/V projection; outputs bf16. XCD-aligned p-groups:
// XCD x (bid%8) handles position groups [64x, 64x+64) = d in [8x, 8x+8).
__global__ __launch_bounds__(256) void k_qkv(const float* __restrict__ skip,
                                             const float* __restrict__ up,
                                             const float* __restrict__ w_qk,
                                             const float* __restrict__ b_qk,
                                             const float* __restrict__ w_v,
                                             const float* __restrict__ b_v,
                                             float* __restrict__ ws) {
  int lane = threadIdx.x & 63;
  int wid  = threadIdx.x >> 6;
  int cs = __builtin_amdgcn_readfirstlane(blockIdx.y * 4 + wid);  // 0..11
  int bidx = ((blockIdx.x & 7) << 6) + (blockIdx.x >> 3);         // XCD align
  int p  = bidx * 64 + lane;
  const float* mr = ws + WS_MR;
  unsigned short* q16 = (unsigned short*)(ws + WS_Q16);
  unsigned short* k16 = (unsigned short*)(ws + WS_K16);
  unsigned short* v16 = (unsigned short*)(ws + WS_V16);
  float acc[16];
  unsigned short* dstu;
  if (cs < 8) {
    int jb = cs * 16;                 // qk column base, uniform
    #pragma unroll
    for (int j = 0; j < 16; j++) acc[j] = b_qk[jb + j];
    const float* w = w_qk + jb;
    #pragma unroll 8
    for (int c = 0; c < NC; c++) {
      float a = (skip[(size_t)c * PTOT + p] - mr[c*2]) * mr[c*2+1];
      #pragma unroll
      for (int j = 0; j < 16; j++)
        acc[j] = fmaf(a, w[c*128 + j], acc[j]);
    }
    dstu = ((jb < 64) ? q16 : k16) + (size_t)p * NC + (jb & 63);
  } else {
    int jb = (cs - 8) * 16;           // v column base, uniform
    #pragma unroll
    for (int j = 0; j < 16; j++) acc[j] = b_v[jb + j];
    const float* w = w_v + jb;
    #pragma unroll 8
    for (int c = 0; c < NC; c++) {
      float a = (up[(size_t)c * PTOT + p] - mr[128 + c*2]) * mr[128 + c*2+1];
      #pragma unroll
      for (int j = 0; j < 16; j++)
        acc[j] = fmaf(a, w[c*64 + j], acc[j]);
    }
    dstu = v16 + (size_t)p * NC + jb;
  }
  unsigned short t[16];
  #pragma unroll
  for (int j = 0; j < 16; j++) {
    __hip_bfloat16 b = __float2bfloat16(acc[j]);   // RNE
    t[j] = *reinterpret_cast<unsigned short*>(&b);
  }
  *(uint4*)(dstu)     = *(const uint4*)(t);
  *(uint4*)(dstu + 8) = *(const uint4*)(t + 8);
}

// Fused attention + output projection with LDS-staged K/V halo.
// Block = 512 threads = 8 waves = 2x4 (d,h) tile. XCD x owns d in [8x,8x+8).
// Stage: K/V rows for d in [dlo,dlo+4), h in [hlo,hlo+6), all w: 192 rows.
__global__ __launch_bounds__(512, 4) void k_attn_proj(const float* __restrict__ rpb,
                                                      const float* __restrict__ w_proj,
                                                      const float* __restrict__ b_proj,
                                                      float* __restrict__ ws,
                                                      float* __restrict__ out) {
  __shared__ unsigned short Ks[SROWS * 64];
  __shared__ unsigned short Vs[SROWS * 64];
  __shared__ float A[64][65];
  __shared__ float rpb_s[NHEADS * 125];

  int tid  = threadIdx.x;
  int wv   = tid >> 6;
  int lane = tid & 63;
  int w    = lane >> 3;
  int head = lane & 7;

  // tile placement: XCD x = bid%8 owns d0 in {8x, 8x+2, 8x+4, 8x+6}
  int x = blockIdx.x & 7;
  int j = blockIdx.x >> 3;            // 0..63
  int d0 = x * 8 + (j >> 4) * TD;
  int h0 = (j & 15) * TH;
  int dlo = min(max(d0 - 1, 0), PD - SD);
  int hlo = min(max(h0 - 1, 0), PH - SH);

  const unsigned short* q16 = (const unsigned short*)(ws + WS_Q16);
  const unsigned short* k16 = (const unsigned short*)(ws + WS_K16);
  const unsigned short* v16 = (const unsigned short*)(ws + WS_V16);

  int d = d0 + (wv >> 2);
  int h = h0 + (wv & 3);
  int p = (d * PH + h) * PW + w;

  // issue q load early (1 uint4/lane), overlap with staging
  uint4 qw = *(const uint4*)(q16 + (size_t)p * NC + head * HD);

  for (int i = tid; i < NHEADS*125; i += 512) rpb_s[i] = rpb[i];

  // ---- stage K/V halo: 4 contiguous spans of 48 rows (6 KB) per tensor ----
  {
    const uint4* kg = (const uint4*)k16;
    const uint4* vg = (const uint4*)v16;
    uint4* ksd = (uint4*)Ks;
    uint4* vsd = (uint4*)Vs;
    #pragma unroll
    for (int it = 0; it < 3; it++) {
      int i = tid + it * 512;         // 0..1535
      int s = i / 384;                // d-span 0..3
      int r = i - s * 384;            // uint4 within span
      int g = ((dlo + s) * PH + hlo) * (PW * NC / 8) + r;  // global uint4 idx
      ksd[i] = kg[g];
      vsd[i] = vg[g];
    }
  }
  __syncthreads();

  int sd = min(max(d - 1, 0), PD - 3);
  int sh = min(max(h - 1, 0), PH - 3);
  int sw = min(max(w - 1, 0), PW - 3);

  int rD[3], rH[3], brd[3], brh[3], brw[3];
  #pragma unroll
  for (int t = 0; t < 3; t++) {
    rD[t] = (sd + t - dlo) * SH;      // d-component of staged row index
    rH[t] = (sh + t - hlo);
    brd[t] = (sd + t - d + 2) * 25;
    brh[t] = (sh + t - h + 2) * 5;
    brw[t] = (sw + t - w + 2);
  }

  float qv[8];
  unpack8(qw, qv);
  const unsigned short* kl = Ks + head * HD;
  const unsigned short* vl = Vs + head * HD;
  int hb = head * 125;

  float lg[27];
  float m = -1e30f;
  #pragma unroll
  for (int jd = 0; jd < 3; jd++)
  #pragma unroll
  for (int jh = 0; jh < 3; jh++)
  #pragma unroll
  for (int jw = 0; jw < 3; jw++) {
    int n = (jd * 3 + jh) * 3 + jw;
    int row = (rD[jd] + rH[jh]) * PW + (sw + jw);
    uint4 kw = *(const uint4*)(kl + row * NC);
    float kv[8];
    unpack8(kw, kv);
    float dot = qv[0]*kv[0] + qv[1]*kv[1] + qv[2]*kv[2] + qv[3]*kv[3]
              + qv[4]*kv[4] + qv[5]*kv[5] + qv[6]*kv[6] + qv[7]*kv[7];
    float l = dot * ATT_SCALE + rpb_s[hb + brd[jd] + brh[jh] + brw[jw]];
    lg[n] = l;
    m = fmaxf(m, l);
  }
  float den = 0.f;
  #pragma unroll
  for (int n = 0; n < 27; n++) {
    float e = __expf(lg[n] - m);
    lg[n] = e;
    den += e;
  }
  float inv = 1.f / den;

  float av[8] = {0,0,0,0,0,0,0,0};
  #pragma unroll
  for (int jd = 0; jd < 3; jd++)
  #pragma unroll
  for (int jh = 0; jh < 3; jh++)
  #pragma unroll
  for (int jw = 0; jw < 3; jw++) {
    int n = (jd * 3 + jh) * 3 + jw;
    int row = (rD[jd] + rH[jh]) * PW + (sw + jw);
    uint4 vw = *(const uint4*)(vl + row * NC);
    float vv[8];
    unpack8(vw, vv);
    float wgt = lg[n];
    #pragma unroll
    for (int i = 0; i < 8; i++) av[i] = fmaf(wgt, vv[i], av[i]);
  }
  int pl = wv * 8 + w;                 // position slot within block
  int cb = head * 8;
  #pragma unroll
  for (int i = 0; i < 8; i++)
    A[pl][cb + i] = av[i] * inv;       // bank = (pl+cb+i)%32: 2-way, free
  __syncthreads();

  // ---- projection: wave wv -> output columns jb..jb+7, 64 positions ----
  int jb = __builtin_amdgcn_readfirstlane(wv * 8);
  int P0 = (d0 * PH + h0) * PW;
  float acc[8];
  #pragma unroll
  for (int jj = 0; jj < 8; jj++) acc[jj] = b_proj[jb + jj];
  #pragma unroll 8
  for (int c = 0; c < NC; c++) {
    float a = A[lane][c];              // stride 65: conflict-free
    #pragma unroll
    for (int jj = 0; jj < 8; jj++)
      acc[jj] = fmaf(a, w_proj[c*64 + jb + jj], acc[jj]);
  }
  // lane's position slot: dl = lane>>5, hl = (lane>>3)&3, w = lane&7
  int pout = P0 + (lane >> 5) * (PH * PW) + ((lane >> 3) & 3) * PW + (lane & 7);
  #pragma unroll
  for (int jj = 0; jj < 8; jj++)
    out[(size_t)(jb + jj) * PTOT + pout] = acc[jj];
}

extern "C" void kernel_launch(void* const* d_in, const int* in_sizes, int n_in,
                              void* d_out, int out_size, void* d_ws, size_t ws_size,
                              hipStream_t stream) {
  const float* skip = (const float*)d_in[0];
  const float* up   = (const float*)d_in[1];
  const float* w_qk = (const float*)d_in[2];
  const float* b_qk = (const float*)d_in[3];
  const float* w_v  = (const float*)d_in[4];
  const float* b_v  = (const float*)d_in[5];
  const float* w_pr = (const float*)d_in[6];
  const float* b_pr = (const float*)d_in[7];
  const float* rpb  = (const float*)d_in[8];
  float* ws  = (float*)d_ws;
  float* out = (float*)d_out;

  k_stats<<<128, 1024, 0, stream>>>(skip, up, ws);
  k_qkv<<<dim3(512, 3), 256, 0, stream>>>(skip, up, w_qk, b_qk, w_v, b_v, ws);
  k_attn_proj<<<512, 512, 0, stream>>>(rpb, w_pr, b_pr, ws, out);
}

// Round 10
// 62.576 us; speedup vs baseline: 1.2930x; 1.2930x over previous
//
#include <hip/hip_runtime.h>
#include <hip/hip_bf16.h>
#include <math.h>

// CrossAttentionModule: 3D neighborhood attention (NATTEN-style clamped window)
// B=1, C=64, D=64, H=64, W=8, HEADS=8, hd=8, K=(3,3,3), dil=1.
//
// R10: back to R8's gather structure (staging regressed: halo re-fetch blew
// FETCH 14->81 MB). New ws layout for q/k/v: [(d,h)][head][w][hd] bf16, so a
// lane's three jw-neighbors are 3 contiguous 16-B chunks (L1 absorbs t=1,2)
// -> 3x fewer L2 line-requests, which was R8's measured bottleneck.

#define PD 64
#define PH 64
#define PW 8
#define PTOT (PD*PH*PW)   // 32768
#define NC 64
#define NHEADS 8
#define HD 8
#define ATT_SCALE 0.35355339059327373f  // 1/sqrt(8)

// ws layout (floats)
#define WS_MR   0                        // 128 tc x {mean,rstd}
#define WS_Q16  1024                     // PTOT*64 ushorts = PTOT*32 floats
#define WS_K16  (WS_Q16 + PTOT*32)
#define WS_V16  (WS_K16 + PTOT*32)
// u16 index within a tensor: (d*64+h)*512 + head*64 + w*8 + hd

__device__ __forceinline__ void unpack8(uint4 u, float f[8]) {
  union { unsigned int i; float x; } a;
  a.i = u.x << 16;          f[0] = a.x;
  a.i = u.x & 0xffff0000u;  f[1] = a.x;
  a.i = u.y << 16;          f[2] = a.x;
  a.i = u.y & 0xffff0000u;  f[3] = a.x;
  a.i = u.z << 16;          f[4] = a.x;
  a.i = u.z & 0xffff0000u;  f[5] = a.x;
  a.i = u.w << 16;          f[6] = a.x;
  a.i = u.w & 0xffff0000u;  f[7] = a.x;
}

__global__ __launch_bounds__(1024) void k_stats(const float* __restrict__ skip,
                                                const float* __restrict__ up,
                                                float* __restrict__ ws) {
  int tc = blockIdx.x;                // 0..127
  const float* src = (tc < 64) ? (skip + (size_t)tc * PTOT)
                               : (up + (size_t)(tc - 64) * PTOT);
  const float4* b4 = (const float4*)src;
  float s1 = 0.f, s2 = 0.f;
  #pragma unroll
  for (int it = 0; it < 8; it++) {
    float4 v = b4[it * 1024 + threadIdx.x];
    s1 += v.x + v.y + v.z + v.w;
    s2 += v.x*v.x + v.y*v.y + v.z*v.z + v.w*v.w;
  }
  #pragma unroll
  for (int off = 32; off; off >>= 1) {
    s1 += __shfl_down(s1, off);
    s2 += __shfl_down(s2, off);
  }
  __shared__ float red[32];
  int wid = threadIdx.x >> 6;
  if ((threadIdx.x & 63) == 0) { red[wid*2] = s1; red[wid*2+1] = s2; }
  __syncthreads();
  if (threadIdx.x == 0) {
    float a = 0.f, b = 0.f;
    #pragma unroll
    for (int w2 = 0; w2 < 16; w2++) { a += red[w2*2]; b += red[w2*2+1]; }
    float mean = a / (float)PTOT;
    float var  = b / (float)PTOT - mean*mean;   // population var (ddof=0)
    ws[WS_MR + tc*2]     = mean;
    ws[WS_MR + tc*2 + 1] = rsqrtf(var + 1e-5f);
  }
}

// Fused inorm + QK/V projection; outputs bf16 in head-major layout.
// grid (512, 3), block 256 (4 waves): cs = blockIdx.y*4+wid in 0..11.
__global__ __launch_bounds__(256) void k_qkv(const float* __restrict__ skip,
                                             const float* __restrict__ up,
                                             const float* __restrict__ w_qk,
                                             const float* __restrict__ b_qk,
                                             const float* __restrict__ w_v,
                                             const float* __restrict__ b_v,
                                             float* __restrict__ ws) {
  int lane = threadIdx.x & 63;
  int wid  = threadIdx.x >> 6;
  int cs = __builtin_amdgcn_readfirstlane(blockIdx.y * 4 + wid);  // 0..11
  int p  = blockIdx.x * 64 + lane;
  const float* mr = ws + WS_MR;
  unsigned short* q16 = (unsigned short*)(ws + WS_Q16);
  unsigned short* k16 = (unsigned short*)(ws + WS_K16);
  unsigned short* v16 = (unsigned short*)(ws + WS_V16);
  float acc[16];
  unsigned short* base;
  int jbl;                             // channel base within its tensor
  if (cs < 8) {
    int jb = cs * 16;                  // qk column base, uniform
    #pragma unroll
    for (int j = 0; j < 16; j++) acc[j] = b_qk[jb + j];
    const float* w = w_qk + jb;
    #pragma unroll 8
    for (int c = 0; c < NC; c++) {
      float a = (skip[(size_t)c * PTOT + p] - mr[c*2]) * mr[c*2+1];
      #pragma unroll
      for (int j = 0; j < 16; j++)
        acc[j] = fmaf(a, w[c*128 + j], acc[j]);
    }
    base = (jb < 64) ? q16 : k16;
    jbl = jb & 63;
  } else {
    int jb = (cs - 8) * 16;            // v column base, uniform
    #pragma unroll
    for (int j = 0; j < 16; j++) acc[j] = b_v[jb + j];
    const float* w = w_v + jb;
    #pragma unroll 8
    for (int c = 0; c < NC; c++) {
      float a = (up[(size_t)c * PTOT + p] - mr[128 + c*2]) * mr[128 + c*2+1];
      #pragma unroll
      for (int j = 0; j < 16; j++)
        acc[j] = fmaf(a, w[c*64 + j], acc[j]);
    }
    base = v16;
    jbl = jb;
  }
  unsigned short t[16];
  #pragma unroll
  for (int j = 0; j < 16; j++) {
    __hip_bfloat16 b = __float2bfloat16(acc[j]);   // RNE
    t[j] = *reinterpret_cast<unsigned short*>(&b);
  }
  // head-major layout: idx = (p>>3)*512 + head*64 + (p&7)*8 + hd
  unsigned short* dst = base + (size_t)(p >> 3) * 512 + (jbl >> 3) * 64 + (p & 7) * 8;
  *(uint4*)(dst)      = *(const uint4*)(t);        // head jbl>>3, hd 0..7
  *(uint4*)(dst + 64) = *(const uint4*)(t + 8);    // head jbl>>3 + 1
}

// Fused attention + output projection, head-major gathers.
// Block = 512 threads = 8 waves = 8 consecutive (d,h) rows = 64 positions.
__global__ __launch_bounds__(512) void k_attn_proj(const float* __restrict__ rpb,
                                                   const float* __restrict__ w_proj,
                                                   const float* __restrict__ b_proj,
                                                   float* __restrict__ ws,
                                                   float* __restrict__ out) {
  __shared__ float A[64][65];
  __shared__ float rpb_s[NHEADS * 125];
  for (int i = threadIdx.x; i < NHEADS*125; i += 512) rpb_s[i] = rpb[i];
  __syncthreads();

  int bid = ((blockIdx.x & 7) << 6) + (blockIdx.x >> 3);   // XCD swizzle

  int wid  = threadIdx.x >> 6;
  int lane = threadIdx.x & 63;
  int job = bid * 8 + wid;
  int d = job >> 6;
  int h = job & 63;
  int w    = lane >> 3;
  int head = lane & 7;

  int sd = min(max(d - 1, 0), PD - 3);
  int sh = min(max(h - 1, 0), PH - 3);
  int sw = min(max(w - 1, 0), PW - 3);

  int brd[3], brh[3], brw[3];
  #pragma unroll
  for (int t = 0; t < 3; t++) {
    brd[t] = (sd + t - d + 2) * 25;
    brh[t] = (sh + t - h + 2) * 5;
    brw[t] = (sw + t - w + 2);
  }

  const unsigned short* q16 = (const unsigned short*)(ws + WS_Q16);
  const unsigned short* k16 = (const unsigned short*)(ws + WS_K16);
  const unsigned short* v16 = (const unsigned short*)(ws + WS_V16);

  int dh = (d << 6) + h;               // d*64+h
  uint4 qw = *(const uint4*)(q16 + (size_t)dh * 512 + head * 64 + w * 8);
  float qv[8];
  unpack8(qw, qv);
  int hb = head * 125;
  int hoff = head * 64 + sw * 8;       // ushort offset of first w-neighbor

  float lg[27];
  float m = -1e30f;
  #pragma unroll
  for (int jd = 0; jd < 3; jd++)
  #pragma unroll
  for (int jh = 0; jh < 3; jh++) {
    int dh2 = ((sd + jd) << 6) + (sh + jh);
    const unsigned short* kdh = k16 + (size_t)dh2 * 512 + hoff;
    #pragma unroll
    for (int t = 0; t < 3; t++) {
      int n = (jd * 3 + jh) * 3 + t;
      uint4 kw = *(const uint4*)(kdh + t * 8);    // 3 contiguous 16B chunks
      float kv[8];
      unpack8(kw, kv);
      float dot = qv[0]*kv[0] + qv[1]*kv[1] + qv[2]*kv[2] + qv[3]*kv[3]
                + qv[4]*kv[4] + qv[5]*kv[5] + qv[6]*kv[6] + qv[7]*kv[7];
      float l = dot * ATT_SCALE + rpb_s[hb + brd[jd] + brh[jh] + brw[t]];
      lg[n] = l;
      m = fmaxf(m, l);
    }
  }
  float den = 0.f;
  #pragma unroll
  for (int n = 0; n < 27; n++) {
    float e = __expf(lg[n] - m);
    lg[n] = e;
    den += e;
  }
  float inv = 1.f / den;

  float av[8] = {0,0,0,0,0,0,0,0};
  #pragma unroll
  for (int jd = 0; jd < 3; jd++)
  #pragma unroll
  for (int jh = 0; jh < 3; jh++) {
    int dh2 = ((sd + jd) << 6) + (sh + jh);
    const unsigned short* vdh = v16 + (size_t)dh2 * 512 + hoff;
    #pragma unroll
    for (int t = 0; t < 3; t++) {
      int n = (jd * 3 + jh) * 3 + t;
      uint4 vw = *(const uint4*)(vdh + t * 8);
      float vv[8];
      unpack8(vw, vv);
      float wgt = lg[n];
      #pragma unroll
      for (int i = 0; i < 8; i++) av[i] = fmaf(wgt, vv[i], av[i]);
    }
  }
  int pl = wid * 8 + w;                // position slot within block (0..63)
  int cb = head * 8;                   // channel base for this lane
  #pragma unroll
  for (int i = 0; i < 8; i++)
    A[pl][cb + i] = av[i] * inv;       // bank = (pl+cb+i)%32: 2-way, free
  __syncthreads();

  // Phase 2: projection. Wave wid handles columns jb..jb+7 for all 64 pos.
  int jb = __builtin_amdgcn_readfirstlane(wid * 8);
  int p0 = bid * 64;
  float acc[8];
  #pragma unroll
  for (int j = 0; j < 8; j++) acc[j] = b_proj[jb + j];
  #pragma unroll 8
  for (int c = 0; c < NC; c++) {
    float a = A[lane][c];              // stride 65: conflict-free
    #pragma unroll
    for (int j = 0; j < 8; j++)
      acc[j] = fmaf(a, w_proj[c*64 + jb + j], acc[j]);
  }
  #pragma unroll
  for (int j = 0; j < 8; j++)
    out[(size_t)(jb + j) * PTOT + p0 + lane] = acc[j];
}

extern "C" void kernel_launch(void* const* d_in, const int* in_sizes, int n_in,
                              void* d_out, int out_size, void* d_ws, size_t ws_size,
                              hipStream_t stream) {
  const float* skip = (const float*)d_in[0];
  const float* up   = (const float*)d_in[1];
  const float* w_qk = (const float*)d_in[2];
  const float* b_qk = (const float*)d_in[3];
  const float* w_v  = (const float*)d_in[4];
  const float* b_v  = (const float*)d_in[5];
  const float* w_pr = (const float*)d_in[6];
  const float* b_pr = (const float*)d_in[7];
  const float* rpb  = (const float*)d_in[8];
  float* ws  = (float*)d_ws;
  float* out = (float*)d_out;

  k_stats<<<128, 1024, 0, stream>>>(skip, up, ws);
  k_qkv<<<dim3(512, 3), 256, 0, stream>>>(skip, up, w_qk, b_qk, w_v, b_v, ws);
  k_attn_proj<<<(PD*PH)/8, 512, 0, stream>>>(rpb, w_pr, b_pr, ws, out);
}